// Round 1
// baseline (1523.491 us; speedup 1.0000x reference)
//
#include <hip/hip_runtime.h>

typedef _Float16 f16;
typedef f16 f16x8 __attribute__((ext_vector_type(8)));
typedef float f32x4 __attribute__((ext_vector_type(4)));

#define NB 16384      // batch rows
#define D 400
#define DP 416        // K padded to multiple of 32
#define LSTR 424      // LDS row stride (f16 elems) to break bank conflicts
#define NEXP 8
#define NTASK 10

static __device__ __forceinline__ f32x4 mfma16x32(f16x8 a, f16x8 b, f32x4 c){
  return __builtin_amdgcn_mfma_f32_16x16x32_f16(a, b, c, 0, 0, 0);
}

// ---------------- prep kernels ----------------

// x[b][0..38]=obs, [39..42]=act, [43..63]=0   (fp16, row stride 64)
__global__ void k_build_x(const float* __restrict__ obs, const float* __restrict__ act,
                          f16* __restrict__ x)
{
  int idx = blockIdx.x*256 + threadIdx.x;     // NB*64 total
  int b = idx >> 6, c = idx & 63;
  float v = 0.f;
  if (c < 39) v = obs[b*39 + c];
  else if (c < 43) v = act[b*4 + (c - 39)];
  x[idx] = (f16)v;
}

// in fp32 [K][N] row-major -> out fp16 [N][Kpad], zero-padded K
__global__ void k_transpose(const float* __restrict__ in, f16* __restrict__ out,
                            int K, int N, int Kpad)
{
  __shared__ float t[32][33];
  int tx = threadIdx.x & 31, ty = threadIdx.x >> 5;   // 256 thr: 32 x 8
  int n0 = blockIdx.x*32, k0 = blockIdx.y*32;
  in  += (size_t)blockIdx.z * K * N;
  out += (size_t)blockIdx.z * N * Kpad;
  #pragma unroll
  for (int r=0;r<4;r++){
    int k = k0 + ty + r*8, nn = n0 + tx;
    t[ty + r*8][tx] = (k < K && nn < N) ? in[(size_t)k*N + nn] : 0.f;
  }
  __syncthreads();
  #pragma unroll
  for (int r=0;r<4;r++){
    int nn = n0 + ty + r*8, kp = k0 + tx;
    if (nn < N && kp < Kpad) out[(size_t)nn*Kpad + kp] = (f16)t[tx][ty + r*8];
  }
}

// fp32 [rows][J] -> fp16 [rows][Jpad], zero pad (value_mat is already [out][k])
__global__ void k_convert_pad(const float* __restrict__ in, f16* __restrict__ out,
                              int rows, int J, int Jpad)
{
  int idx = blockIdx.x*256 + threadIdx.x;
  if (idx >= rows*Jpad) return;
  int jp = idx % Jpad, r = idx / Jpad;
  out[idx] = (jp < J) ? (f16)in[(size_t)r*J + jp] : (f16)0.f;
}

// kq[n][t][j] = sum_i key_mat[n][i][j] * tq[t][i]     (fp32, [8][10][400])
__global__ void k_kq(const float* __restrict__ key_mat, const float* __restrict__ tq,
                     float* __restrict__ kq)
{
  __shared__ float tqs[NTASK*D];
  int n = blockIdx.x, tid = threadIdx.x;
  for (int i=tid;i<NTASK*D;i+=256) tqs[i] = tq[i];
  __syncthreads();
  float a0[NTASK], a1[NTASK];
  #pragma unroll
  for (int t=0;t<NTASK;t++){ a0[t]=0.f; a1[t]=0.f; }
  const float* km = key_mat + (size_t)n*D*D;
  for (int i=0;i<D;i++){
    float v0 = km[(size_t)i*D + tid];
    float v1 = (tid+256 < D) ? km[(size_t)i*D + tid + 256] : 0.f;
    #pragma unroll
    for (int t=0;t<NTASK;t++){
      float q = tqs[t*D + i];
      a0[t] += v0*q; a1[t] += v1*q;
    }
  }
  #pragma unroll
  for (int t=0;t<NTASK;t++){
    kq[(size_t)n*NTASK*D + t*D + tid] = a0[t];
    if (tid+256 < D) kq[(size_t)n*NTASK*D + t*D + tid+256] = a1[t];
  }
}

// ---------------- fused compute kernels ----------------
// common geometry: 256 thr = 4 waves, block owns 64 rows, wave wv owns rows wv*16..+15.
// MFMA 16x16x32 f16: A lane: row=l&15, k=(l>>4)*8+e ; B lane: col=l&15, k=(l>>4)*8+e ;
// D lane: col=l&15, row=(l>>4)*4+r.

__global__ __launch_bounds__(256,2) void k_backbone(
    const f16* __restrict__ x, const f16* __restrict__ w1T, const float* __restrict__ b1,
    const f16* __restrict__ w2T, const float* __restrict__ b2, f16* __restrict__ h16)
{
  __shared__ f16 lact[64*LSTR];
  __shared__ float bias1[D], bias2[D];
  const int tid = threadIdx.x;
  const int lane = tid & 63, wv = tid >> 6;
  const int l15 = lane & 15, lhi = lane >> 4;
  const int rowbase = blockIdx.x * 64;
  const int rb4 = wv*16 + lhi*4;
  const f32x4 Z4 = {0.f,0.f,0.f,0.f};

  for (int i=tid;i<D;i+=256){ bias1[i]=b1[i]; bias2[i]=b2[i]; }

  f32x4 acc[25];
  #pragma unroll
  for (int i=0;i<25;i++) acc[i]=Z4;

  { // GEMM1: [64x64] x [64 -> 400]
    const f16* Arow = x + (size_t)(rowbase + wv*16 + l15)*64 + lhi*8;
    const f16* Brow = w1T + (size_t)l15*64 + lhi*8;
    #pragma unroll
    for (int kt=0;kt<2;kt++){
      f16x8 a = *(const f16x8*)(Arow + kt*32);
      #pragma unroll
      for (int nt=0;nt<25;nt++){
        f16x8 b = *(const f16x8*)(Brow + nt*16*64 + kt*32);
        acc[nt] = mfma16x32(a,b,acc[nt]);
      }
    }
  }
  __syncthreads();   // bias staged; lact not yet touched
  #pragma unroll
  for (int nt=0;nt<25;nt++){
    int col = nt*16 + l15;
    float bv = bias1[col];
    #pragma unroll
    for (int r=0;r<4;r++){
      float v = acc[nt][r] + bv; v = v>0.f?v:0.f;
      lact[(rb4+r)*LSTR + col] = (f16)v;
    }
  }
  for (int i=tid;i<64*16;i+=256) lact[(i>>4)*LSTR + 400 + (i&15)] = (f16)0.f;
  __syncthreads();

  #pragma unroll
  for (int i=0;i<25;i++) acc[i]=Z4;
  { // GEMM2: K=416 from LDS
    const f16* Arow = lact + (wv*16 + l15)*LSTR + lhi*8;
    const f16* Brow = w2T + (size_t)l15*DP + lhi*8;
    for (int kt=0;kt<13;kt++){
      f16x8 a = *(const f16x8*)(Arow + kt*32);
      #pragma unroll
      for (int nt=0;nt<25;nt++){
        f16x8 b = *(const f16x8*)(Brow + (size_t)nt*16*DP + kt*32);
        acc[nt] = mfma16x32(a,b,acc[nt]);
      }
    }
  }
  #pragma unroll
  for (int nt=0;nt<25;nt++){
    int col = nt*16 + l15;
    float bv = bias2[col];
    #pragma unroll
    for (int r=0;r<4;r++){
      float v = acc[nt][r] + bv; v = v>0.f?v:0.f;
      h16[(size_t)(rowbase + rb4 + r)*DP + col] = (f16)v;
    }
  }
  for (int i=tid;i<64*16;i+=256)
    h16[(size_t)(rowbase + (i>>4))*DP + 400 + (i&15)] = (f16)0.f;
}

__global__ __launch_bounds__(256,2) void k_experts(
    const f16* __restrict__ h16, const f16* __restrict__ w1T, const float* __restrict__ b1s,
    const f16* __restrict__ w2T, const float* __restrict__ b2s,
    f16* __restrict__ e16, const float* __restrict__ kq, const int* __restrict__ task,
    float* __restrict__ scores)
{
  __shared__ f16 lact[64*LSTR];
  __shared__ float bias1[D], bias2[D];
  __shared__ float kqs[NTASK*D];
  __shared__ int tasks[64];
  const int tid = threadIdx.x;
  const int lane = tid & 63, wv = tid >> 6;
  const int l15 = lane & 15, lhi = lane >> 4;
  const int n = blockIdx.y;
  const int rowbase = blockIdx.x * 64;
  const int rb4 = wv*16 + lhi*4;
  const f32x4 Z4 = {0.f,0.f,0.f,0.f};

  for (int i=tid;i<D;i+=256){ bias1[i]=b1s[n*D+i]; bias2[i]=b2s[n*D+i]; }
  for (int i=tid;i<NTASK*D;i+=256) kqs[i] = kq[(size_t)n*NTASK*D + i];
  if (tid < 64) tasks[tid] = task[rowbase + tid];

  f32x4 acc[25];
  #pragma unroll
  for (int i=0;i<25;i++) acc[i]=Z4;

  { // expert layer 1: h @ ex_w1[n]
    const f16* Arow = h16 + (size_t)(rowbase + wv*16 + l15)*DP + lhi*8;
    const f16* Brow = w1T + (size_t)n*D*DP + (size_t)l15*DP + lhi*8;
    for (int kt=0;kt<13;kt++){
      f16x8 a = *(const f16x8*)(Arow + kt*32);
      #pragma unroll
      for (int nt=0;nt<25;nt++){
        f16x8 b = *(const f16x8*)(Brow + (size_t)nt*16*DP + kt*32);
        acc[nt] = mfma16x32(a,b,acc[nt]);
      }
    }
  }
  __syncthreads();
  #pragma unroll
  for (int nt=0;nt<25;nt++){
    int col = nt*16 + l15;
    float bv = bias1[col];
    #pragma unroll
    for (int r=0;r<4;r++){
      float v = acc[nt][r] + bv; v = v>0.f?v:0.f;
      lact[(rb4+r)*LSTR + col] = (f16)v;
    }
  }
  for (int i=tid;i<64*16;i+=256) lact[(i>>4)*LSTR + 400 + (i&15)] = (f16)0.f;
  __syncthreads();

  #pragma unroll
  for (int i=0;i<25;i++) acc[i]=Z4;
  { // expert layer 2 from LDS
    const f16* Arow = lact + (wv*16 + l15)*LSTR + lhi*8;
    const f16* Brow = w2T + (size_t)n*D*DP + (size_t)l15*DP + lhi*8;
    for (int kt=0;kt<13;kt++){
      f16x8 a = *(const f16x8*)(Arow + kt*32);
      #pragma unroll
      for (int nt=0;nt<25;nt++){
        f16x8 b = *(const f16x8*)(Brow + (size_t)nt*16*DP + kt*32);
        acc[nt] = mfma16x32(a,b,acc[nt]);
      }
    }
  }
  // epilogue: e2 = relu(acc+b2); store fp16; score partial = e2 . kq[n][task[b]]
  int t_[4]; size_t eb[4]; float p_[4];
  #pragma unroll
  for (int r=0;r<4;r++){
    t_[r] = tasks[rb4 + r];
    eb[r] = ((size_t)n*NB + rowbase + rb4 + r)*DP;
    p_[r] = 0.f;
  }
  #pragma unroll
  for (int nt=0;nt<25;nt++){
    int col = nt*16 + l15;
    float bv = bias2[col];
    #pragma unroll
    for (int r=0;r<4;r++){
      float v = acc[nt][r] + bv; v = v>0.f?v:0.f;
      e16[eb[r] + col] = (f16)v;
      p_[r] += v * kqs[t_[r]*D + col];
    }
  }
  #pragma unroll
  for (int r=0;r<4;r++){
    float p = p_[r];
    p += __shfl_xor(p, 1, 64);
    p += __shfl_xor(p, 2, 64);
    p += __shfl_xor(p, 4, 64);
    p += __shfl_xor(p, 8, 64);
    if (l15 == 0) scores[(size_t)(rowbase + rb4 + r)*NEXP + n] = p;
  }
  for (int i=tid;i<64*16;i+=256)
    e16[((size_t)n*NB + rowbase + (i>>4))*DP + 400 + (i&15)] = (f16)0.f;
}

// tower: softmax over experts, weighted value-GEMMs, 3-layer MLP.
// 512 thr = 8 waves: wq=wv&3 -> row quarter (16 rows); w2=wv>>2 -> col half.
// col tiles: nt0 = w2*12, 13 tiles each (tile 12 overlaps, identical values -> benign).
__global__ __launch_bounds__(512,2) void k_tower(
    const f16* __restrict__ e16, const f16* __restrict__ valT, const float* __restrict__ scores,
    const f16* __restrict__ tw1T, const float* __restrict__ tb1,
    const f16* __restrict__ tw2T, const float* __restrict__ tb2,
    const float* __restrict__ tw3, const float* __restrict__ tb3,
    float* __restrict__ out)
{
  __shared__ f16 lact[64*LSTR];
  __shared__ float wsm[64*NEXP];
  __shared__ float bias1[D], bias2[D], w3s[D];
  __shared__ float psum[64][2];
  const int tid = threadIdx.x;
  const int lane = tid & 63, wv = tid >> 6;
  const int l15 = lane & 15, lhi = lane >> 4;
  const int wq = wv & 3, w2 = wv >> 2;
  const int rowbase = blockIdx.x * 64;
  const int nt0 = w2*12;
  const int rb4 = wq*16 + lhi*4;
  const f32x4 Z4 = {0.f,0.f,0.f,0.f};

  for (int i=tid;i<D;i+=512){ bias1[i]=tb1[i]; bias2[i]=tb2[i]; w3s[i]=tw3[i]; }
  if (tid < 64){
    const float* sr = scores + (size_t)(rowbase + tid)*NEXP;
    float s[8]; float m = -1e30f;
    #pragma unroll
    for (int k=0;k<8;k++){ s[k]=sr[k]; m = fmaxf(m, s[k]); }
    float sum = 0.f;
    #pragma unroll
    for (int k=0;k<8;k++){ s[k] = expf(s[k]-m); sum += s[k]; }
    float inv = 1.f/sum;
    #pragma unroll
    for (int k=0;k<8;k++) wsm[tid*NEXP + k] = s[k]*inv;
  }
  __syncthreads();

  // weighted per-expert value GEMMs -> tower_in
  f32x4 tsum[13];
  #pragma unroll
  for (int i=0;i<13;i++) tsum[i]=Z4;
  for (int n=0;n<NEXP;n++){
    f32x4 acc[13];
    #pragma unroll
    for (int i=0;i<13;i++) acc[i]=Z4;
    const f16* Arow = e16 + ((size_t)n*NB + rowbase + wq*16 + l15)*DP + lhi*8;
    const f16* Brow = valT + (size_t)n*D*DP + (size_t)(nt0*16 + l15)*DP + lhi*8;
    for (int kt=0;kt<13;kt++){
      f16x8 a = *(const f16x8*)(Arow + kt*32);
      #pragma unroll
      for (int j=0;j<13;j++){
        f16x8 b = *(const f16x8*)(Brow + (size_t)j*16*DP + kt*32);
        acc[j] = mfma16x32(a,b,acc[j]);
      }
    }
    float wn[4];
    #pragma unroll
    for (int r=0;r<4;r++) wn[r] = wsm[(rb4+r)*NEXP + n];
    #pragma unroll
    for (int j=0;j<13;j++){
      #pragma unroll
      for (int r=0;r<4;r++) tsum[j][r] += acc[j][r]*wn[r];
    }
  }
  // tower_in -> LDS fp16
  #pragma unroll
  for (int j=0;j<13;j++){
    int col = (nt0+j)*16 + l15;
    #pragma unroll
    for (int r=0;r<4;r++) lact[(rb4+r)*LSTR + col] = (f16)tsum[j][r];
  }
  for (int i=tid;i<64*16;i+=512) lact[(i>>4)*LSTR + 400 + (i&15)] = (f16)0.f;
  __syncthreads();

  // tower L1
  f32x4 acc[13];
  #pragma unroll
  for (int i=0;i<13;i++) acc[i]=Z4;
  {
    const f16* Arow = lact + (wq*16 + l15)*LSTR + lhi*8;
    const f16* Brow = tw1T + (size_t)(nt0*16 + l15)*DP + lhi*8;
    for (int kt=0;kt<13;kt++){
      f16x8 a = *(const f16x8*)(Arow + kt*32);
      #pragma unroll
      for (int j=0;j<13;j++){
        f16x8 b = *(const f16x8*)(Brow + (size_t)j*16*DP + kt*32);
        acc[j] = mfma16x32(a,b,acc[j]);
      }
    }
  }
  __syncthreads();   // everyone done reading tower_in
  #pragma unroll
  for (int j=0;j<13;j++){
    int col = (nt0+j)*16 + l15;
    float bv = bias1[col];
    #pragma unroll
    for (int r=0;r<4;r++){
      float v = acc[j][r] + bv; v = v>0.f?v:0.f;
      lact[(rb4+r)*LSTR + col] = (f16)v;
    }
  }
  __syncthreads();

  // tower L2
  #pragma unroll
  for (int i=0;i<13;i++) acc[i]=Z4;
  {
    const f16* Arow = lact + (wq*16 + l15)*LSTR + lhi*8;
    const f16* Brow = tw2T + (size_t)(nt0*16 + l15)*DP + lhi*8;
    for (int kt=0;kt<13;kt++){
      f16x8 a = *(const f16x8*)(Arow + kt*32);
      #pragma unroll
      for (int j=0;j<13;j++){
        f16x8 b = *(const f16x8*)(Brow + (size_t)j*16*DP + kt*32);
        acc[j] = mfma16x32(a,b,acc[j]);
      }
    }
  }
  // tower L3: dot(relu(acc+b2), w3); skip overlapped tile for w2==1
  float p_[4] = {0.f,0.f,0.f,0.f};
  #pragma unroll
  for (int j=0;j<13;j++){
    int col = (nt0+j)*16 + l15;
    float bv = bias2[col];
    float wv3 = w3s[col];
    #pragma unroll
    for (int r=0;r<4;r++){
      float v = acc[j][r] + bv; v = v>0.f?v:0.f;
      if (!(w2 == 1 && j == 0)) p_[r] += v * wv3;
    }
  }
  #pragma unroll
  for (int r=0;r<4;r++){
    float p = p_[r];
    p += __shfl_xor(p, 1, 64);
    p += __shfl_xor(p, 2, 64);
    p += __shfl_xor(p, 4, 64);
    p += __shfl_xor(p, 8, 64);
    if (l15 == 0) psum[rb4 + r][w2] = p;
  }
  __syncthreads();
  if (tid < 64) out[rowbase + tid] = psum[tid][0] + psum[tid][1] + tb3[0];
}

// ---------------- launcher ----------------

extern "C" void kernel_launch(void* const* d_in, const int* in_sizes, int n_in,
                              void* d_out, int out_size, void* d_ws, size_t ws_size,
                              hipStream_t stream)
{
  const float* obs     = (const float*)d_in[0];
  const float* act     = (const float*)d_in[1];
  const int*   task    = (const int*)  d_in[2];
  const float* bb_w1   = (const float*)d_in[3];
  const float* bb_b1   = (const float*)d_in[4];
  const float* bb_w2   = (const float*)d_in[5];
  const float* bb_b2   = (const float*)d_in[6];
  const float* ex_w1   = (const float*)d_in[7];
  const float* ex_b1   = (const float*)d_in[8];
  const float* ex_w2   = (const float*)d_in[9];
  const float* ex_b2   = (const float*)d_in[10];
  const float* key_mat = (const float*)d_in[11];
  const float* val_mat = (const float*)d_in[12];
  const float* tq      = (const float*)d_in[13];
  const float* tw_w1   = (const float*)d_in[14];
  const float* tw_b1   = (const float*)d_in[15];
  const float* tw_w2   = (const float*)d_in[16];
  const float* tw_b2   = (const float*)d_in[17];
  const float* tw_w3   = (const float*)d_in[18];
  const float* tw_b3   = (const float*)d_in[19];

  char* ws = (char*)d_ws;
  size_t off = 0;
  auto alloc = [&](size_t bytes){ void* p = ws + off; off += (bytes + 255) & ~(size_t)255; return p; };
  f16*   x16   = (f16*)  alloc((size_t)NB*64*2);
  f16*   h16   = (f16*)  alloc((size_t)NB*DP*2);
  f16*   e16   = (f16*)  alloc((size_t)NEXP*NB*DP*2);
  float* scors = (float*)alloc((size_t)NB*NEXP*4);
  float* kq    = (float*)alloc((size_t)NEXP*NTASK*D*4);
  f16*   bbw1T = (f16*)  alloc((size_t)D*64*2);
  f16*   bbw2T = (f16*)  alloc((size_t)D*DP*2);
  f16*   exw1T = (f16*)  alloc((size_t)NEXP*D*DP*2);
  f16*   exw2T = (f16*)  alloc((size_t)NEXP*D*DP*2);
  f16*   valT  = (f16*)  alloc((size_t)NEXP*D*DP*2);
  f16*   tw1T  = (f16*)  alloc((size_t)D*DP*2);
  f16*   tw2T  = (f16*)  alloc((size_t)D*DP*2);
  (void)ws_size; (void)in_sizes; (void)n_in; (void)out_size;

  k_build_x<<<NB*64/256, 256, 0, stream>>>(obs, act, x16);
  k_transpose<<<dim3(13, 2, 1),  256, 0, stream>>>(bb_w1, bbw1T, 43, D, 64);
  k_transpose<<<dim3(13,13, 1),  256, 0, stream>>>(bb_w2, bbw2T, D, D, DP);
  k_transpose<<<dim3(13,13, 8),  256, 0, stream>>>(ex_w1, exw1T, D, D, DP);
  k_transpose<<<dim3(13,13, 8),  256, 0, stream>>>(ex_w2, exw2T, D, D, DP);
  k_transpose<<<dim3(13,13, 1),  256, 0, stream>>>(tw_w1, tw1T,  D, D, DP);
  k_transpose<<<dim3(13,13, 1),  256, 0, stream>>>(tw_w2, tw2T,  D, D, DP);
  k_convert_pad<<<(NEXP*D*DP + 255)/256, 256, 0, stream>>>(val_mat, valT, NEXP*D, D, DP);
  k_kq<<<NEXP, 256, 0, stream>>>(key_mat, tq, kq);

  k_backbone<<<NB/64, 256, 0, stream>>>(x16, bbw1T, bb_b1, bbw2T, bb_b2, h16);
  k_experts<<<dim3(NB/64, NEXP), 256, 0, stream>>>(h16, exw1T, ex_b1, exw2T, ex_b2,
                                                   e16, kq, task, scors);
  k_tower<<<NB/64, 512, 0, stream>>>(e16, valT, scors, tw1T, tw_b1, tw2T, tw_b2,
                                     tw_w3, tw_b3, (float*)d_out);
}

// Round 2
// 544.703 us; speedup vs baseline: 2.7969x; 2.7969x over previous
//
#include <hip/hip_runtime.h>

typedef _Float16 f16;
typedef f16 f16x8 __attribute__((ext_vector_type(8)));
typedef float f32x4 __attribute__((ext_vector_type(4)));

#define NB 16384      // batch rows
#define D 400
#define DP 416        // padded dim: 13 * 32
#define LSTR 424      // LDS activation row stride (f16) -> 848B, granule stride 53 (5 mod 8): conflict-spread
#define NEXP 8
#define NTASK 10
#define NKT 13        // K tiles of 32

static __device__ __forceinline__ f32x4 mfma16x32(f16x8 a, f16x8 b, f32x4 c){
  return __builtin_amdgcn_mfma_f32_16x16x32_f16(a, b, c, 0, 0, 0);
}

static __device__ __forceinline__ void g2l(const void* g, void* l){
  __builtin_amdgcn_global_load_lds(
      (const __attribute__((address_space(1))) void*)g,
      (__attribute__((address_space(3))) void*)l, 16, 0, 0);
}

// Stage a [nch*16 rows][32 k] f16 slice into LDS (linear [rows][64B]).
// src_base must already include the kt byte offset. One g2l = 16 rows (1KB).
static __device__ __forceinline__ void stage_tile(const char* src_base, size_t rstride,
                                                  char* lds_base, int nch, int wv, int lane){
  const char* s = src_base + (size_t)(lane >> 2)*rstride + (size_t)(lane & 3)*16;
  for (int c = wv; c < nch; c += 4)
    g2l(s + (size_t)c*16*rstride, lds_base + (size_t)c*1024);
}

static __device__ __forceinline__ f16x8 scale8(f16x8 a, f16 s){
  f16x8 r;
  #pragma unroll
  for (int e=0;e<8;e++) r[e] = a[e]*s;
  return r;
}

// ---------------- prep kernels ----------------

__global__ void k_build_x(const float* __restrict__ obs, const float* __restrict__ act,
                          f16* __restrict__ x)
{
  int idx = blockIdx.x*256 + threadIdx.x;     // NB*64
  int b = idx >> 6, c = idx & 63;
  float v = 0.f;
  if (c < 39) v = obs[b*39 + c];
  else if (c < 43) v = act[b*4 + (c - 39)];
  x[idx] = (f16)v;
}

// fp32 [K][N] -> fp16 [Npad][Kpad], zero padded both dims
__global__ void k_transpose(const float* __restrict__ in, f16* __restrict__ out,
                            int K, int N, int Kpad, int Npad)
{
  __shared__ float t[32][33];
  int tx = threadIdx.x & 31, ty = threadIdx.x >> 5;
  int n0 = blockIdx.x*32, k0 = blockIdx.y*32;
  in  += (size_t)blockIdx.z * K * N;
  out += (size_t)blockIdx.z * Npad * Kpad;
  #pragma unroll
  for (int r=0;r<4;r++){
    int k = k0 + ty + r*8, nn = n0 + tx;
    t[ty + r*8][tx] = (k < K && nn < N) ? in[(size_t)k*N + nn] : 0.f;
  }
  __syncthreads();
  #pragma unroll
  for (int r=0;r<4;r++){
    int nn = n0 + ty + r*8, kp = k0 + tx;
    if (nn < Npad && kp < Kpad) out[(size_t)nn*Kpad + kp] = (f16)t[tx][ty + r*8];
  }
}

// value_mat fp32 [8][400][400] ([out][k]) -> fp16 [8][416][416] zero-padded
__global__ void k_val_pad(const float* __restrict__ in, f16* __restrict__ out)
{
  int idx = blockIdx.x*256 + threadIdx.x;
  if (idx >= NEXP*DP*DP) return;
  int c = idx % DP, r = (idx / DP) % DP, n = idx / (DP*DP);
  float v = (r < D && c < D) ? in[((size_t)n*D + r)*D + c] : 0.f;
  out[idx] = (f16)v;
}

// kq[n][t][j] = sum_i key_mat[n][i][j] * tq[t][i]   fp32 [8][10][416], cols>=400 zero
__global__ void k_kq(const float* __restrict__ key_mat, const float* __restrict__ tq,
                     float* __restrict__ kq)
{
  __shared__ float tqs[NTASK*D];
  int n = blockIdx.x, tid = threadIdx.x;
  for (int i=tid;i<NTASK*D;i+=256) tqs[i] = tq[i];
  __syncthreads();
  float a0[NTASK], a1[NTASK];
  #pragma unroll
  for (int t=0;t<NTASK;t++){ a0[t]=0.f; a1[t]=0.f; }
  const float* km = key_mat + (size_t)n*D*D;
  for (int i=0;i<D;i++){
    float v0 = km[(size_t)i*D + tid];
    float v1 = (tid+256 < D) ? km[(size_t)i*D + tid + 256] : 0.f;
    #pragma unroll
    for (int t=0;t<NTASK;t++){
      float q = tqs[t*D + i];
      a0[t] += v0*q; a1[t] += v1*q;
    }
  }
  #pragma unroll
  for (int t=0;t<NTASK;t++){
    kq[(size_t)n*NTASK*DP + t*DP + tid] = a0[t];
    if (tid+256 < DP) kq[(size_t)n*NTASK*DP + t*DP + tid+256] = (tid+256 < D) ? a1[t] : 0.f;
  }
}

// ---------------- fused compute kernels ----------------
// 256 thr = 4 waves. Block: 64 rows x 416 cols. Wave (rh,ch): rows rh*32..+31, col tiles ch*13..+12.
// MFMA 16x16x32 f16. A lane: row=l15,k=lhi*8+e; B lane: col=l15,k=lhi*8+e; D lane: col=l15,row=lhi*4+r.
// Staged slice layout: [rows][32k] f16 linear (64B rows); frag read = elem row*32 + lhi*8.

#define GEMM_STEP_SLICE(bufA, bufB) do {                                        \
    f16x8 a0 = *(const f16x8*)((bufA) + (rh*32      + l15)*32 + lhi*8);         \
    f16x8 a1 = *(const f16x8*)((bufA) + (rh*32 + 16 + l15)*32 + lhi*8);         \
    _Pragma("unroll")                                                           \
    for (int j=0;j<13;j++){                                                     \
      f16x8 b = *(const f16x8*)((bufB) + ((ch*13+j)*16 + l15)*32 + lhi*8);      \
      acc[0][j] = mfma16x32(a0, b, acc[0][j]);                                  \
      acc[1][j] = mfma16x32(a1, b, acc[1][j]);                                  \
    }                                                                           \
  } while(0)

#define GEMM_STEP_LACT(kt, bufB) do {                                           \
    f16x8 a0 = *(const f16x8*)(lact + (rh*32      + l15)*LSTR + (kt)*32 + lhi*8); \
    f16x8 a1 = *(const f16x8*)(lact + (rh*32 + 16 + l15)*LSTR + (kt)*32 + lhi*8); \
    _Pragma("unroll")                                                           \
    for (int j=0;j<13;j++){                                                     \
      f16x8 b = *(const f16x8*)((bufB) + ((ch*13+j)*16 + l15)*32 + lhi*8);      \
      acc[0][j] = mfma16x32(a0, b, acc[0][j]);                                  \
      acc[1][j] = mfma16x32(a1, b, acc[1][j]);                                  \
    }                                                                           \
  } while(0)

#define ZERO_ACC() do { _Pragma("unroll") for (int j=0;j<13;j++){ acc[0][j]=Z4; acc[1][j]=Z4; } } while(0)

__global__ __launch_bounds__(256,1) void k_backbone(
    const f16* __restrict__ x, const f16* __restrict__ w1T, const float* __restrict__ b1,
    const f16* __restrict__ w2T, const float* __restrict__ b2, f16* __restrict__ h16)
{
  __shared__ f16 bufB[2][26*16*32];
  __shared__ f16 bufA[2][64*32];
  __shared__ f16 lact[64*LSTR];
  __shared__ float bias1[DP], bias2[DP];
  const int tid = threadIdx.x;
  const int lane = tid & 63, wv = tid >> 6;
  const int l15 = lane & 15, lhi = lane >> 4;
  const int rh = wv >> 1, ch = wv & 1;
  const int rowbase = blockIdx.x * 64;
  const f32x4 Z4 = {0.f,0.f,0.f,0.f};
  f32x4 acc[2][13];

  for (int i=tid;i<DP;i+=256){ bias1[i] = (i<D)? b1[i] : 0.f; bias2[i] = (i<D)? b2[i] : 0.f; }

  const char* xb = (const char*)x + (size_t)rowbase*128;
  // L1: K=64, 2 kt steps
  ZERO_ACC();
  stage_tile((const char*)w1T, 128, (char*)bufB[0], 26, wv, lane);
  stage_tile(xb, 128, (char*)bufA[0], 4, wv, lane);
  __syncthreads();
  for (int kt=0; kt<2; kt++){
    int cur = kt & 1;
    if (kt < 1){
      stage_tile((const char*)w1T + 64, 128, (char*)bufB[1], 26, wv, lane);
      stage_tile(xb + 64, 128, (char*)bufA[1], 4, wv, lane);
    }
    GEMM_STEP_SLICE(bufA[cur], bufB[cur]);
    __syncthreads();
  }
  stage_tile((const char*)w2T, 832, (char*)bufB[0], 26, wv, lane);
  #pragma unroll
  for (int j=0;j<13;j++){
    int col = (ch*13+j)*16 + l15;
    float bv = bias1[col];
    #pragma unroll
    for (int ar=0;ar<2;ar++)
      #pragma unroll
      for (int r=0;r<4;r++){
        float v = acc[ar][j][r] + bv; v = v>0.f?v:0.f;
        lact[(rh*32+ar*16+lhi*4+r)*LSTR + col] = (f16)v;
      }
  }
  __syncthreads();

  // L2: K=416
  ZERO_ACC();
  for (int kt=0; kt<NKT; kt++){
    int cur = kt & 1;
    if (kt < NKT-1)
      stage_tile((const char*)w2T + (size_t)(kt+1)*64, 832, (char*)bufB[cur^1], 26, wv, lane);
    GEMM_STEP_LACT(kt, bufB[cur]);
    __syncthreads();
  }
  #pragma unroll
  for (int j=0;j<13;j++){
    int col = (ch*13+j)*16 + l15;
    float bv = bias2[col];
    #pragma unroll
    for (int ar=0;ar<2;ar++)
      #pragma unroll
      for (int r=0;r<4;r++){
        float v = acc[ar][j][r] + bv; v = v>0.f?v:0.f;
        h16[(size_t)(rowbase + rh*32+ar*16+lhi*4+r)*DP + col] = (f16)v;
      }
  }
}

__global__ __launch_bounds__(256,1) void k_experts(
    const f16* __restrict__ h16, const f16* __restrict__ w1T, const float* __restrict__ b1s,
    const f16* __restrict__ w2T, const float* __restrict__ b2s,
    f16* __restrict__ e16, const float* __restrict__ kqg, const int* __restrict__ task,
    float* __restrict__ scores)
{
  __shared__ f16 bufB[2][26*16*32];
  __shared__ f16 bufA[2][64*32];
  __shared__ f16 lact[64*LSTR];
  __shared__ float bias1[DP], bias2[DP];
  __shared__ float kqs[NTASK*420];
  __shared__ float psum[64][2];
  __shared__ int tasks[64];
  const int tid = threadIdx.x;
  const int lane = tid & 63, wv = tid >> 6;
  const int l15 = lane & 15, lhi = lane >> 4;
  const int rh = wv >> 1, ch = wv & 1;
  const int n = blockIdx.x;                  // expert-major: XCD = n (L2-resident weights)
  const int rowbase = blockIdx.y * 64;
  const f32x4 Z4 = {0.f,0.f,0.f,0.f};
  f32x4 acc[2][13];

  for (int i=tid;i<DP;i+=256){
    bias1[i] = (i<D)? b1s[n*D+i] : 0.f;
    bias2[i] = (i<D)? b2s[n*D+i] : 0.f;
  }
  for (int i=tid;i<NTASK*DP;i+=256) kqs[(i/DP)*420 + (i%DP)] = kqg[(size_t)n*NTASK*DP + i];
  if (tid < 64) tasks[tid] = task[rowbase + tid];

  const f16* wb1 = w1T + (size_t)n*DP*DP;
  const f16* wb2 = w2T + (size_t)n*DP*DP;
  const char* hb = (const char*)h16 + (size_t)rowbase*832;

  // L1
  ZERO_ACC();
  stage_tile((const char*)wb1, 832, (char*)bufB[0], 26, wv, lane);
  stage_tile(hb, 832, (char*)bufA[0], 4, wv, lane);
  __syncthreads();
  for (int kt=0; kt<NKT; kt++){
    int cur = kt & 1;
    if (kt < NKT-1){
      stage_tile((const char*)wb1 + (size_t)(kt+1)*64, 832, (char*)bufB[cur^1], 26, wv, lane);
      stage_tile(hb + (size_t)(kt+1)*64, 832, (char*)bufA[cur^1], 4, wv, lane);
    }
    GEMM_STEP_SLICE(bufA[cur], bufB[cur]);
    __syncthreads();
  }
  stage_tile((const char*)wb2, 832, (char*)bufB[0], 26, wv, lane);
  #pragma unroll
  for (int j=0;j<13;j++){
    int col = (ch*13+j)*16 + l15;
    float bv = bias1[col];
    #pragma unroll
    for (int ar=0;ar<2;ar++)
      #pragma unroll
      for (int r=0;r<4;r++){
        float v = acc[ar][j][r] + bv; v = v>0.f?v:0.f;
        lact[(rh*32+ar*16+lhi*4+r)*LSTR + col] = (f16)v;
      }
  }
  __syncthreads();

  // L2
  ZERO_ACC();
  for (int kt=0; kt<NKT; kt++){
    int cur = kt & 1;
    if (kt < NKT-1)
      stage_tile((const char*)wb2 + (size_t)(kt+1)*64, 832, (char*)bufB[cur^1], 26, wv, lane);
    GEMM_STEP_LACT(kt, bufB[cur]);
    __syncthreads();
  }
  // epilogue: relu+bias -> e16 (f16), score partials vs kq
  int t_[2][4];
  #pragma unroll
  for (int ar=0;ar<2;ar++)
    #pragma unroll
    for (int r=0;r<4;r++) t_[ar][r] = tasks[rh*32+ar*16+lhi*4+r];
  float p_[2][4] = {{0.f,0.f,0.f,0.f},{0.f,0.f,0.f,0.f}};
  #pragma unroll
  for (int j=0;j<13;j++){
    int col = (ch*13+j)*16 + l15;
    float bv = bias2[col];
    #pragma unroll
    for (int ar=0;ar<2;ar++)
      #pragma unroll
      for (int r=0;r<4;r++){
        float v = acc[ar][j][r] + bv; v = v>0.f?v:0.f;
        e16[((size_t)n*NB + rowbase + rh*32+ar*16+lhi*4+r)*DP + col] = (f16)v;
        p_[ar][r] += v * kqs[t_[ar][r]*420 + col];
      }
  }
  #pragma unroll
  for (int ar=0;ar<2;ar++)
    #pragma unroll
    for (int r=0;r<4;r++){
      float p = p_[ar][r];
      p += __shfl_xor(p, 1, 64);
      p += __shfl_xor(p, 2, 64);
      p += __shfl_xor(p, 4, 64);
      p += __shfl_xor(p, 8, 64);
      if (l15 == 0) psum[rh*32+ar*16+lhi*4+r][ch] = p;
    }
  __syncthreads();
  if (tid < 64) scores[(size_t)(rowbase + tid)*NEXP + n] = psum[tid][0] + psum[tid][1];
}

__global__ __launch_bounds__(256,1) void k_tower(
    const f16* __restrict__ e16, const f16* __restrict__ valT, const float* __restrict__ scores,
    const f16* __restrict__ tw1T, const float* __restrict__ tb1,
    const f16* __restrict__ tw2T, const float* __restrict__ tb2,
    const float* __restrict__ tw3, const float* __restrict__ tb3,
    float* __restrict__ out)
{
  __shared__ f16 bufB[2][26*16*32];
  __shared__ f16 bufA[2][64*32];
  __shared__ f16 lact[64*LSTR];
  __shared__ float bias1[DP], bias2[DP];
  __shared__ float w3s[DP];
  __shared__ float wsm[64*NEXP];
  __shared__ float psum[64][2];
  const int tid = threadIdx.x;
  const int lane = tid & 63, wv = tid >> 6;
  const int l15 = lane & 15, lhi = lane >> 4;
  const int rh = wv >> 1, ch = wv & 1;
  const int rowbase = blockIdx.x * 64;
  const f32x4 Z4 = {0.f,0.f,0.f,0.f};
  f32x4 acc[2][13];

  for (int i=tid;i<DP;i+=256){
    bias1[i] = (i<D)? tb1[i] : 0.f;
    bias2[i] = (i<D)? tb2[i] : 0.f;
    w3s[i]   = (i<D)? tw3[i] : 0.f;
  }
  if (tid < 64){
    const float* sr = scores + (size_t)(rowbase + tid)*NEXP;
    float s[8]; float m = -1e30f;
    #pragma unroll
    for (int k=0;k<8;k++){ s[k]=sr[k]; m = fmaxf(m, s[k]); }
    float sum = 0.f;
    #pragma unroll
    for (int k=0;k<8;k++){ s[k] = expf(s[k]-m); sum += s[k]; }
    float inv = 1.f/sum;
    #pragma unroll
    for (int k=0;k<8;k++) wsm[tid*NEXP + k] = s[k]*inv;
  }

  // weighted value GEMMs: acc over all 8 experts, A scaled by softmax weight
  ZERO_ACC();
  stage_tile((const char*)valT, 832, (char*)bufB[0], 26, wv, lane);
  stage_tile((const char*)e16 + (size_t)rowbase*832, 832, (char*)bufA[0], 4, wv, lane);
  __syncthreads();
  for (int n=0;n<NEXP;n++){
    for (int kt=0;kt<NKT;kt++){
      int cur = (n + kt) & 1;
      int k2 = kt+1, n2 = n;
      if (k2 == NKT){ k2 = 0; n2 = n+1; }
      if (n2 < NEXP){
        stage_tile((const char*)(valT + (size_t)n2*DP*DP) + (size_t)k2*64, 832,
                   (char*)bufB[cur^1], 26, wv, lane);
        stage_tile((const char*)(e16 + ((size_t)n2*NB + rowbase)*DP) + (size_t)k2*64, 832,
                   (char*)bufA[cur^1], 4, wv, lane);
      }
      f16 w0 = (f16)wsm[(rh*32      + l15)*NEXP + n];
      f16 w1 = (f16)wsm[(rh*32 + 16 + l15)*NEXP + n];
      f16x8 a0 = scale8(*(const f16x8*)(bufA[cur] + (rh*32      + l15)*32 + lhi*8), w0);
      f16x8 a1 = scale8(*(const f16x8*)(bufA[cur] + (rh*32 + 16 + l15)*32 + lhi*8), w1);
      #pragma unroll
      for (int j=0;j<13;j++){
        f16x8 b = *(const f16x8*)(bufB[cur] + ((ch*13+j)*16 + l15)*32 + lhi*8);
        acc[0][j] = mfma16x32(a0, b, acc[0][j]);
        acc[1][j] = mfma16x32(a1, b, acc[1][j]);
      }
      __syncthreads();
    }
  }
  stage_tile((const char*)tw1T, 832, (char*)bufB[0], 26, wv, lane);
  #pragma unroll
  for (int j=0;j<13;j++){
    int col = (ch*13+j)*16 + l15;
    #pragma unroll
    for (int ar=0;ar<2;ar++)
      #pragma unroll
      for (int r=0;r<4;r++)
        lact[(rh*32+ar*16+lhi*4+r)*LSTR + col] = (f16)acc[ar][j][r];
  }
  __syncthreads();

  // tower L1
  ZERO_ACC();
  for (int kt=0; kt<NKT; kt++){
    int cur = kt & 1;
    if (kt < NKT-1)
      stage_tile((const char*)tw1T + (size_t)(kt+1)*64, 832, (char*)bufB[cur^1], 26, wv, lane);
    GEMM_STEP_LACT(kt, bufB[cur]);
    __syncthreads();
  }
  stage_tile((const char*)tw2T, 832, (char*)bufB[0], 26, wv, lane);
  #pragma unroll
  for (int j=0;j<13;j++){
    int col = (ch*13+j)*16 + l15;
    float bv = bias1[col];
    #pragma unroll
    for (int ar=0;ar<2;ar++)
      #pragma unroll
      for (int r=0;r<4;r++){
        float v = acc[ar][j][r] + bv; v = v>0.f?v:0.f;
        lact[(rh*32+ar*16+lhi*4+r)*LSTR + col] = (f16)v;
      }
  }
  __syncthreads();

  // tower L2
  ZERO_ACC();
  for (int kt=0; kt<NKT; kt++){
    int cur = kt & 1;
    if (kt < NKT-1)
      stage_tile((const char*)tw2T + (size_t)(kt+1)*64, 832, (char*)bufB[cur^1], 26, wv, lane);
    GEMM_STEP_LACT(kt, bufB[cur]);
    __syncthreads();
  }
  // tower L3: dot(relu(acc+b2), w3)
  float p_[2][4] = {{0.f,0.f,0.f,0.f},{0.f,0.f,0.f,0.f}};
  #pragma unroll
  for (int j=0;j<13;j++){
    int col = (ch*13+j)*16 + l15;
    float bv = bias2[col];
    float wv3 = w3s[col];
    #pragma unroll
    for (int ar=0;ar<2;ar++)
      #pragma unroll
      for (int r=0;r<4;r++){
        float v = acc[ar][j][r] + bv; v = v>0.f?v:0.f;
        p_[ar][r] += v * wv3;
      }
  }
  #pragma unroll
  for (int ar=0;ar<2;ar++)
    #pragma unroll
    for (int r=0;r<4;r++){
      float p = p_[ar][r];
      p += __shfl_xor(p, 1, 64);
      p += __shfl_xor(p, 2, 64);
      p += __shfl_xor(p, 4, 64);
      p += __shfl_xor(p, 8, 64);
      if (l15 == 0) psum[rh*32+ar*16+lhi*4+r][ch] = p;
    }
  __syncthreads();
  if (tid < 64) out[rowbase + tid] = psum[tid][0] + psum[tid][1] + tb3[0];
}

// ---------------- launcher ----------------

extern "C" void kernel_launch(void* const* d_in, const int* in_sizes, int n_in,
                              void* d_out, int out_size, void* d_ws, size_t ws_size,
                              hipStream_t stream)
{
  const float* obs     = (const float*)d_in[0];
  const float* act     = (const float*)d_in[1];
  const int*   task    = (const int*)  d_in[2];
  const float* bb_w1   = (const float*)d_in[3];
  const float* bb_b1   = (const float*)d_in[4];
  const float* bb_w2   = (const float*)d_in[5];
  const float* bb_b2   = (const float*)d_in[6];
  const float* ex_w1   = (const float*)d_in[7];
  const float* ex_b1   = (const float*)d_in[8];
  const float* ex_w2   = (const float*)d_in[9];
  const float* ex_b2   = (const float*)d_in[10];
  const float* key_mat = (const float*)d_in[11];
  const float* val_mat = (const float*)d_in[12];
  const float* tq      = (const float*)d_in[13];
  const float* tw_w1   = (const float*)d_in[14];
  const float* tw_b1   = (const float*)d_in[15];
  const float* tw_w2   = (const float*)d_in[16];
  const float* tw_b2   = (const float*)d_in[17];
  const float* tw_w3   = (const float*)d_in[18];
  const float* tw_b3   = (const float*)d_in[19];

  char* ws = (char*)d_ws;
  size_t off = 0;
  auto alloc = [&](size_t bytes){ void* p = ws + off; off += (bytes + 255) & ~(size_t)255; return p; };
  f16*   x16   = (f16*)  alloc((size_t)NB*64*2);
  f16*   h16   = (f16*)  alloc((size_t)NB*DP*2);
  f16*   e16   = (f16*)  alloc((size_t)NEXP*NB*DP*2);
  float* scors = (float*)alloc((size_t)NB*NEXP*4);
  float* kq    = (float*)alloc((size_t)NEXP*NTASK*DP*4);
  f16*   bbw1T = (f16*)  alloc((size_t)DP*64*2);
  f16*   bbw2T = (f16*)  alloc((size_t)DP*DP*2);
  f16*   exw1T = (f16*)  alloc((size_t)NEXP*DP*DP*2);
  f16*   exw2T = (f16*)  alloc((size_t)NEXP*DP*DP*2);
  f16*   valT  = (f16*)  alloc((size_t)NEXP*DP*DP*2);
  f16*   tw1T  = (f16*)  alloc((size_t)DP*DP*2);
  f16*   tw2T  = (f16*)  alloc((size_t)DP*DP*2);
  (void)ws_size; (void)in_sizes; (void)n_in; (void)out_size;

  k_build_x<<<NB*64/256, 256, 0, stream>>>(obs, act, x16);
  k_transpose<<<dim3(13, 2, 1),  256, 0, stream>>>(bb_w1, bbw1T, 43, D, 64, DP);
  k_transpose<<<dim3(13,13, 1),  256, 0, stream>>>(bb_w2, bbw2T, D, D, DP, DP);
  k_transpose<<<dim3(13,13, 8),  256, 0, stream>>>(ex_w1, exw1T, D, D, DP, DP);
  k_transpose<<<dim3(13,13, 8),  256, 0, stream>>>(ex_w2, exw2T, D, D, DP, DP);
  k_transpose<<<dim3(13,13, 1),  256, 0, stream>>>(tw_w1, tw1T,  D, D, DP, DP);
  k_transpose<<<dim3(13,13, 1),  256, 0, stream>>>(tw_w2, tw2T,  D, D, DP, DP);
  k_val_pad<<<(NEXP*DP*DP + 255)/256, 256, 0, stream>>>(val_mat, valT);
  k_kq<<<NEXP, 256, 0, stream>>>(key_mat, tq, kq);

  k_backbone<<<NB/64, 256, 0, stream>>>(x16, bbw1T, bb_b1, bbw2T, bb_b2, h16);
  k_experts<<<dim3(NEXP, NB/64), 256, 0, stream>>>(h16, exw1T, ex_b1, exw2T, ex_b2,
                                                   e16, kq, task, scors);
  k_tower<<<NB/64, 256, 0, stream>>>(e16, valT, scors, tw1T, tw_b1, tw2T, tw_b2,
                                     tw_w3, tw_b3, (float*)d_out);
}

// Round 4
// 431.460 us; speedup vs baseline: 3.5310x; 1.2625x over previous
//
#include <hip/hip_runtime.h>

typedef _Float16 f16;
typedef f16 f16x8 __attribute__((ext_vector_type(8)));
typedef float f32x4 __attribute__((ext_vector_type(4)));

#define NB 16384
#define D 400
#define DP 416
#define NEXP 8
#define NTASK 10
#define NKT 13

static __device__ __forceinline__ f32x4 mfma16x32(f16x8 a, f16x8 b, f32x4 c){
  return __builtin_amdgcn_mfma_f32_16x16x32_f16(a, b, c, 0, 0, 0);
}
static __device__ __forceinline__ void g2l(const void* g, void* l){
  __builtin_amdgcn_global_load_lds((const __attribute__((address_space(1))) void*)g,
      (__attribute__((address_space(3))) void*)l, 16, 0, 0);
}
static __device__ __forceinline__ f16x8 scale8(f16x8 a, f16 s){
  f16x8 r;
  #pragma unroll
  for (int e=0;e<8;e++) r[e] = a[e]*s;
  return r;
}

// ---- swizzled duo staging -------------------------------------------------
// A "duo" = two adjacent 16-col j-tiles for one kt: [16 rows][128B], XOR-swizzled
// by chunk ^= (row&7). LDS dest linear (g2l scatters lane*16); global source
// pre-swizzled. Weight matrices are [416][416] f16 (832B rows), k-contiguous.
static __device__ __forceinline__ void stageB(const char* wbase, char* lds, int kt,
                                              int t0, int nduo, int wv, int nwv, int lane){
  const int r = lane >> 3, c = lane & 7, cg = c ^ r;
  const int n2 = nduo*2;
  for (int u = wv; u < n2; u += nwv){
    int dd = u >> 1, h = u & 1;
    g2l(wbase + (size_t)((t0 + dd*2 + (cg>>2))*16 + h*8 + r)*832 + (size_t)kt*64 + (cg&3)*16,
        lds + dd*2048 + h*1024);
  }
}
// read B-frag: duo-local dloc, tile parity t, MFMA B-lane (col=l15, k=lhi*8+e)
static __device__ __forceinline__ f16x8 rdB(const f16* buf, int dloc, int t, int lhi, int l15){
  return *(const f16x8*)(buf + dloc*1024 + l15*64 + ((((t*4+lhi) ^ (l15&7)))<<3));
}
// lact: [128][416] f16, XOR-swizzled on 16B chunks (only chunks <48; 48..51 linear)
static __device__ __forceinline__ f16x8 rdL(const f16* lact, int r, int kt, int lhi){
  int q = kt*4 + lhi;
  int c = (q < 48) ? (q ^ (r&7)) : q;
  return *(const f16x8*)(lact + r*416 + (c<<3));
}
static __device__ __forceinline__ int lact_idx(int r, int col){
  int q = col >> 3;
  int c = (q < 48) ? (q ^ (r&7)) : q;
  return r*416 + (c<<3) + (col&7);
}

// ---------------- prep kernels ----------------

__global__ void k_build_x(const float* __restrict__ obs, const float* __restrict__ act,
                          f16* __restrict__ x)
{
  int idx = blockIdx.x*256 + threadIdx.x;
  int b = idx >> 6, c = idx & 63;
  float v = 0.f;
  if (c < 39) v = obs[b*39 + c];
  else if (c < 43) v = act[b*4 + (c - 39)];
  x[idx] = (f16)v;
}

__global__ void k_transpose(const float* __restrict__ in, f16* __restrict__ out,
                            int K, int N, int Kpad, int Npad)
{
  __shared__ float t[32][33];
  int tx = threadIdx.x & 31, ty = threadIdx.x >> 5;
  int n0 = blockIdx.x*32, k0 = blockIdx.y*32;
  in  += (size_t)blockIdx.z * K * N;
  out += (size_t)blockIdx.z * Npad * Kpad;
  #pragma unroll
  for (int r=0;r<4;r++){
    int k = k0 + ty + r*8, nn = n0 + tx;
    t[ty + r*8][tx] = (k < K && nn < N) ? in[(size_t)k*N + nn] : 0.f;
  }
  __syncthreads();
  #pragma unroll
  for (int r=0;r<4;r++){
    int nn = n0 + ty + r*8, kp = k0 + tx;
    if (nn < Npad && kp < Kpad) out[(size_t)nn*Kpad + kp] = (f16)t[tx][ty + r*8];
  }
}

__global__ void k_val_pad(const float* __restrict__ in, f16* __restrict__ out)
{
  int idx = blockIdx.x*256 + threadIdx.x;
  if (idx >= NEXP*DP*DP) return;
  int c = idx % DP, r = (idx / DP) % DP, n = idx / (DP*DP);
  float v = (r < D && c < D) ? in[((size_t)n*D + r)*D + c] : 0.f;
  out[idx] = (f16)v;
}

__global__ void k_kq(const float* __restrict__ key_mat, const float* __restrict__ tq,
                     float* __restrict__ kq)
{
  __shared__ float tqs[NTASK*D];
  int n = blockIdx.x, tid = threadIdx.x;
  for (int i=tid;i<NTASK*D;i+=256) tqs[i] = tq[i];
  __syncthreads();
  float a0[NTASK], a1[NTASK];
  #pragma unroll
  for (int t=0;t<NTASK;t++){ a0[t]=0.f; a1[t]=0.f; }
  const float* km = key_mat + (size_t)n*D*D;
  for (int i=0;i<D;i++){
    float v0 = km[(size_t)i*D + tid];
    float v1 = (tid+256 < D) ? km[(size_t)i*D + tid + 256] : 0.f;
    #pragma unroll
    for (int t=0;t<NTASK;t++){
      float q = tqs[t*D + i];
      a0[t] += v0*q; a1[t] += v1*q;
    }
  }
  #pragma unroll
  for (int t=0;t<NTASK;t++){
    kq[(size_t)n*NTASK*DP + t*DP + tid] = a0[t];
    if (tid+256 < DP) kq[(size_t)n*NTASK*DP + t*DP + tid+256] = (tid+256 < D) ? a1[t] : 0.f;
  }
}

// ---------------- compute kernels ----------------
// 8-wave kernels: 512 thr, BM=128 rows. wave (rh=wv>>1, ch=wv&1): rows rh*32..+31,
// col tiles ch*13..+12. A from global regs (prefetch 1 kt) or lact. acc[2][13].

#define ZERO_ACC() do { _Pragma("unroll") for (int j=0;j<13;j++){ acc[0][j]=Z4; acc[1][j]=Z4; } } while(0)

#define COMPUTE26(a0_, a1_, BUF) do {                                           \
    __builtin_amdgcn_s_setprio(1);                                              \
    _Pragma("unroll")                                                           \
    for (int j=0;j<13;j++){                                                     \
      int tj = ch*13 + j;                                                       \
      f16x8 b = rdB((BUF), tj>>1, tj&1, lhi, l15);                              \
      acc[0][j] = mfma16x32((a0_), b, acc[0][j]);                               \
      acc[1][j] = mfma16x32((a1_), b, acc[1][j]);                               \
    }                                                                           \
    __builtin_amdgcn_s_setprio(0);                                              \
  } while(0)

__global__ __launch_bounds__(512,2) void k_backbone(
    const f16* __restrict__ x, const f16* __restrict__ w1T, const float* __restrict__ b1,
    const f16* __restrict__ w2T, const float* __restrict__ b2, f16* __restrict__ h16)
{
  __shared__ f16 bufB[2][13*1024];
  __shared__ f16 lact[128*416];
  const int tid = threadIdx.x, lane = tid & 63, wv = tid >> 6;
  const int l15 = lane & 15, lhi = lane >> 4;
  const int rh = wv >> 1, ch = wv & 1;
  const int rowbase = blockIdx.x * 128;
  const f32x4 Z4 = {0,0,0,0};
  f32x4 acc[2][13];

  // GEMM1: K=64. B1 = w1T [416][64] (128B rows): stage all 26 tiles FLAT:
  // tile dd at byte dd*2048 = [16 rows][128B] (full K=64), chunk ^= (row&7).
  { int r = lane>>3, c = lane&7, cg = c ^ r;
    for (int u = wv; u < 52; u += 8){
      int dd = u>>1, h = u&1;
      g2l((const char*)w1T + (size_t)(dd*16 + h*8 + r)*128 + cg*16,
          (char*)bufB[0] + dd*2048 + h*1024);
    }
  }
  ZERO_ACC();
  const f16* Ab = x + (size_t)(rowbase + rh*32 + l15)*64;
  __syncthreads();
  // FLAT tile read: tile tj at f16 offset tj*1024, k-chunk index kt*4+lhi (8 chunks/row)
  #pragma unroll
  for (int kt=0; kt<2; kt++){
    f16x8 a0 = *(const f16x8*)(Ab + kt*32 + lhi*8);
    f16x8 a1 = *(const f16x8*)(Ab + 16*64 + kt*32 + lhi*8);
    __builtin_amdgcn_s_setprio(1);
    #pragma unroll
    for (int j=0;j<13;j++){
      int tj = ch*13 + j;
      f16x8 b = rdB(bufB[0], tj, kt, lhi, l15);
      acc[0][j] = mfma16x32(a0, b, acc[0][j]);
      acc[1][j] = mfma16x32(a1, b, acc[1][j]);
    }
    __builtin_amdgcn_s_setprio(0);
  }
  __syncthreads();
  stageB((const char*)w2T, (char*)bufB[0], 0, 0, 13, wv, 8, lane);
  #pragma unroll
  for (int j=0;j<13;j++){
    int col = (ch*13+j)*16 + l15;
    float bv = (col<D)? b1[col] : 0.f;
    #pragma unroll
    for (int ar=0;ar<2;ar++)
      #pragma unroll
      for (int rr=0;rr<4;rr++){
        float v = acc[ar][j][rr] + bv; v = v>0.f?v:0.f;
        int r = rh*32 + ar*16 + lhi*4 + rr;
        lact[lact_idx(r, col)] = (f16)v;
      }
  }
  __syncthreads();

  // GEMM2: K=416, A from lact
  ZERO_ACC();
  for (int kt=0; kt<NKT; kt++){
    if (kt<NKT-1) stageB((const char*)w2T, (char*)bufB[(kt+1)&1], kt+1, 0, 13, wv, 8, lane);
    f16x8 a0 = rdL(lact, rh*32 + l15, kt, lhi);
    f16x8 a1 = rdL(lact, rh*32 + 16 + l15, kt, lhi);
    COMPUTE26(a0, a1, bufB[kt&1]);
    __syncthreads();
  }
  #pragma unroll
  for (int j=0;j<13;j++){
    int col = (ch*13+j)*16 + l15;
    float bv = (col<D)? b2[col] : 0.f;
    #pragma unroll
    for (int ar=0;ar<2;ar++)
      #pragma unroll
      for (int rr=0;rr<4;rr++){
        float v = acc[ar][j][rr] + bv; v = v>0.f?v:0.f;
        h16[(size_t)(rowbase + rh*32+ar*16+lhi*4+rr)*DP + col] = (f16)v;
      }
  }
}

__global__ __launch_bounds__(512,2) void k_experts(
    const f16* __restrict__ h16, const f16* __restrict__ w1T, const float* __restrict__ b1s,
    const f16* __restrict__ w2T, const float* __restrict__ b2s,
    f16* __restrict__ e16, const float* __restrict__ kqg, const int* __restrict__ task,
    float* __restrict__ scores)
{
  __shared__ f16 bufB[2][13*1024];
  __shared__ f16 lact[128*416];
  __shared__ float psum[128][2];
  const int tid = threadIdx.x, lane = tid & 63, wv = tid >> 6;
  const int l15 = lane & 15, lhi = lane >> 4;
  const int rh = wv >> 1, ch = wv & 1;
  const int n = blockIdx.x;
  const int rowbase = blockIdx.y * 128;
  const f32x4 Z4 = {0,0,0,0};
  f32x4 acc[2][13];

  const char* wb1 = (const char*)(w1T + (size_t)n*DP*DP);
  const char* wb2 = (const char*)(w2T + (size_t)n*DP*DP);

  // GEMM1: A = h16 (global, reg-prefetched)
  ZERO_ACC();
  stageB(wb1, (char*)bufB[0], 0, 0, 13, wv, 8, lane);
  const f16* Ab = h16 + (size_t)(rowbase + rh*32 + l15)*DP;
  f16x8 a0 = *(const f16x8*)(Ab + lhi*8);
  f16x8 a1 = *(const f16x8*)(Ab + 16*DP + lhi*8);
  __syncthreads();
  for (int kt=0; kt<NKT; kt++){
    f16x8 a0n=a0, a1n=a1;
    if (kt<NKT-1){
      stageB(wb1, (char*)bufB[(kt+1)&1], kt+1, 0, 13, wv, 8, lane);
      a0n = *(const f16x8*)(Ab + (kt+1)*32 + lhi*8);
      a1n = *(const f16x8*)(Ab + 16*DP + (kt+1)*32 + lhi*8);
    }
    COMPUTE26(a0, a1, bufB[kt&1]);
    __syncthreads();
    a0=a0n; a1=a1n;
  }
  stageB(wb2, (char*)bufB[0], 0, 0, 13, wv, 8, lane);
  #pragma unroll
  for (int j=0;j<13;j++){
    int col = (ch*13+j)*16 + l15;
    float bv = (col<D)? b1s[n*D+col] : 0.f;
    #pragma unroll
    for (int ar=0;ar<2;ar++)
      #pragma unroll
      for (int rr=0;rr<4;rr++){
        float v = acc[ar][j][rr] + bv; v = v>0.f?v:0.f;
        int r = rh*32 + ar*16 + lhi*4 + rr;
        lact[lact_idx(r, col)] = (f16)v;
      }
  }
  __syncthreads();

  // GEMM2: A from lact
  ZERO_ACC();
  for (int kt=0; kt<NKT; kt++){
    if (kt<NKT-1) stageB(wb2, (char*)bufB[(kt+1)&1], kt+1, 0, 13, wv, 8, lane);
    f16x8 ax0 = rdL(lact, rh*32 + l15, kt, lhi);
    f16x8 ax1 = rdL(lact, rh*32 + 16 + l15, kt, lhi);
    COMPUTE26(ax0, ax1, bufB[kt&1]);
    __syncthreads();
  }
  // epilogue: e16 + score partials
  const float* kqp[2][4];
  const float* kqb = kqg + (size_t)n*NTASK*DP;
  #pragma unroll
  for (int ar=0;ar<2;ar++)
    #pragma unroll
    for (int rr=0;rr<4;rr++){
      int grow = rowbase + rh*32 + ar*16 + lhi*4 + rr;
      kqp[ar][rr] = kqb + (size_t)task[grow]*DP;
    }
  float p_[2][4] = {{0,0,0,0},{0,0,0,0}};
  #pragma unroll
  for (int j=0;j<13;j++){
    int col = (ch*13+j)*16 + l15;
    float bv = (col<D)? b2s[n*D+col] : 0.f;
    #pragma unroll
    for (int ar=0;ar<2;ar++)
      #pragma unroll
      for (int rr=0;rr<4;rr++){
        float v = acc[ar][j][rr] + bv; v = v>0.f?v:0.f;
        e16[((size_t)n*NB + rowbase + rh*32+ar*16+lhi*4+rr)*DP + col] = (f16)v;
        p_[ar][rr] += v * kqp[ar][rr][col];
      }
  }
  #pragma unroll
  for (int ar=0;ar<2;ar++)
    #pragma unroll
    for (int rr=0;rr<4;rr++){
      float p = p_[ar][rr];
      p += __shfl_xor(p, 1, 64);
      p += __shfl_xor(p, 2, 64);
      p += __shfl_xor(p, 4, 64);
      p += __shfl_xor(p, 8, 64);
      if (l15 == 0) psum[rh*32+ar*16+lhi*4+rr][ch] = p;
    }
  __syncthreads();
  if (tid < 128) scores[(size_t)(rowbase + tid)*NEXP + n] = psum[tid][0] + psum[tid][1];
}

// attn: softmax + 8 weighted value-GEMMs -> ti16. Col-split blocks for occupancy.
// 256 thr, 4 waves, BM=64 rows (wave = 16 rows). colh0: tiles 0..13 (7 duos),
// colh1: tiles 14..25 (6 duos).
__global__ __launch_bounds__(256,3) void k_attn(
    const f16* __restrict__ e16, const f16* __restrict__ valT,
    const float* __restrict__ scores, f16* __restrict__ ti16)
{
  __shared__ f16 bufB[2][7*1024];
  __shared__ float wsm[64*NEXP];
  const int tid = threadIdx.x, lane = tid & 63, wv = tid >> 6;
  const int l15 = lane & 15, lhi = lane >> 4;
  const int colh = blockIdx.x;
  const int rowbase = blockIdx.y * 64;
  const int nd = colh ? 6 : 7;
  const int t0 = colh * 14;
  const f32x4 Z4 = {0,0,0,0};
  f32x4 acc[14];
  #pragma unroll
  for (int j=0;j<14;j++) acc[j]=Z4;

  if (tid < 64){
    const float* sr = scores + (size_t)(rowbase + tid)*NEXP;
    float s[8]; float m = -1e30f;
    #pragma unroll
    for (int k=0;k<8;k++){ s[k]=sr[k]; m = fmaxf(m, s[k]); }
    float sum = 0.f;
    #pragma unroll
    for (int k=0;k<8;k++){ s[k] = expf(s[k]-m); sum += s[k]; }
    float inv = 1.f/sum;
    #pragma unroll
    for (int k=0;k<8;k++) wsm[tid*NEXP + k] = s[k]*inv;
  }

  const f16* Arow = e16 + (size_t)(rowbase + wv*16 + l15)*DP;
  stageB((const char*)valT, (char*)bufB[0], 0, t0, nd, wv, 4, lane);
  f16x8 a = *(const f16x8*)(Arow + lhi*8);
  __syncthreads();

  for (int n=0;n<NEXP;n++){
    f16 wn = (f16)wsm[(wv*16+l15)*NEXP + n];
    for (int kt=0;kt<NKT;kt++){
      int s = n*NKT + kt;
      f16x8 an = a;
      if (s < NEXP*NKT-1){
        int n2 = (kt==NKT-1)? n+1 : n, k2 = (kt==NKT-1)? 0 : kt+1;
        stageB((const char*)(valT + (size_t)n2*DP*DP), (char*)bufB[(s+1)&1], k2, t0, nd, wv, 4, lane);
        an = *(const f16x8*)(Arow + (size_t)n2*NB*DP + k2*32 + lhi*8);
      }
      f16x8 as = scale8(a, wn);
      __builtin_amdgcn_s_setprio(1);
      #pragma unroll
      for (int dd=0;dd<7;dd++) if (dd<nd){
        f16x8 b0 = rdB(bufB[s&1], dd, 0, lhi, l15);
        f16x8 b1 = rdB(bufB[s&1], dd, 1, lhi, l15);
        acc[dd*2]   = mfma16x32(as, b0, acc[dd*2]);
        acc[dd*2+1] = mfma16x32(as, b1, acc[dd*2+1]);
      }
      __builtin_amdgcn_s_setprio(0);
      __syncthreads();
      a = an;
    }
  }
  #pragma unroll
  for (int dd=0;dd<7;dd++) if (dd<nd)
    #pragma unroll
    for (int t2=0;t2<2;t2++){
      int j = dd*2+t2;
      int col = (t0 + j)*16 + l15;
      #pragma unroll
      for (int rr=0;rr<4;rr++)
        ti16[(size_t)(rowbase + wv*16 + lhi*4 + rr)*DP + col] = (f16)acc[j][rr];
    }
}

__global__ __launch_bounds__(512,2) void k_mlp3(
    const f16* __restrict__ ti16,
    const f16* __restrict__ tw1T, const float* __restrict__ tb1,
    const f16* __restrict__ tw2T, const float* __restrict__ tb2,
    const float* __restrict__ tw3, const float* __restrict__ tb3,
    float* __restrict__ out)
{
  __shared__ f16 bufB[2][13*1024];
  __shared__ f16 lact[128*416];
  __shared__ float psum[128][2];
  const int tid = threadIdx.x, lane = tid & 63, wv = tid >> 6;
  const int l15 = lane & 15, lhi = lane >> 4;
  const int rh = wv >> 1, ch = wv & 1;
  const int rowbase = blockIdx.x * 128;
  const f32x4 Z4 = {0,0,0,0};
  f32x4 acc[2][13];

  // GEMM1: A = ti16 global
  ZERO_ACC();
  stageB((const char*)tw1T, (char*)bufB[0], 0, 0, 13, wv, 8, lane);
  const f16* Ab = ti16 + (size_t)(rowbase + rh*32 + l15)*DP;
  f16x8 a0 = *(const f16x8*)(Ab + lhi*8);
  f16x8 a1 = *(const f16x8*)(Ab + 16*DP + lhi*8);
  __syncthreads();
  for (int kt=0; kt<NKT; kt++){
    f16x8 a0n=a0, a1n=a1;
    if (kt<NKT-1){
      stageB((const char*)tw1T, (char*)bufB[(kt+1)&1], kt+1, 0, 13, wv, 8, lane);
      a0n = *(const f16x8*)(Ab + (kt+1)*32 + lhi*8);
      a1n = *(const f16x8*)(Ab + 16*DP + (kt+1)*32 + lhi*8);
    }
    COMPUTE26(a0, a1, bufB[kt&1]);
    __syncthreads();
    a0=a0n; a1=a1n;
  }
  stageB((const char*)tw2T, (char*)bufB[0], 0, 0, 13, wv, 8, lane);
  #pragma unroll
  for (int j=0;j<13;j++){
    int col = (ch*13+j)*16 + l15;
    float bv = (col<D)? tb1[col] : 0.f;
    #pragma unroll
    for (int ar=0;ar<2;ar++)
      #pragma unroll
      for (int rr=0;rr<4;rr++){
        float v = acc[ar][j][rr] + bv; v = v>0.f?v:0.f;
        int r = rh*32 + ar*16 + lhi*4 + rr;
        lact[lact_idx(r, col)] = (f16)v;
      }
  }
  __syncthreads();

  // GEMM2
  ZERO_ACC();
  for (int kt=0; kt<NKT; kt++){
    if (kt<NKT-1) stageB((const char*)tw2T, (char*)bufB[(kt+1)&1], kt+1, 0, 13, wv, 8, lane);
    f16x8 ax0 = rdL(lact, rh*32 + l15, kt, lhi);
    f16x8 ax1 = rdL(lact, rh*32 + 16 + l15, kt, lhi);
    COMPUTE26(ax0, ax1, bufB[kt&1]);
    __syncthreads();
  }
  // L3 dot
  float p_[2][4] = {{0,0,0,0},{0,0,0,0}};
  #pragma unroll
  for (int j=0;j<13;j++){
    int col = (ch*13+j)*16 + l15;
    float bv = (col<D)? tb2[col] : 0.f;
    float w3 = (col<D)? tw3[col] : 0.f;
    #pragma unroll
    for (int ar=0;ar<2;ar++)
      #pragma unroll
      for (int rr=0;rr<4;rr++){
        float v = acc[ar][j][rr] + bv; v = v>0.f?v:0.f;
        p_[ar][rr] += v * w3;
      }
  }
  #pragma unroll
  for (int ar=0;ar<2;ar++)
    #pragma unroll
    for (int rr=0;rr<4;rr++){
      float p = p_[ar][rr];
      p += __shfl_xor(p, 1, 64);
      p += __shfl_xor(p, 2, 64);
      p += __shfl_xor(p, 4, 64);
      p += __shfl_xor(p, 8, 64);
      if (l15 == 0) psum[rh*32+ar*16+lhi*4+rr][ch] = p;
    }
  __syncthreads();
  if (tid < 128) out[rowbase + tid] = psum[tid][0] + psum[tid][1] + tb3[0];
}

// ---------------- launcher ----------------

extern "C" void kernel_launch(void* const* d_in, const int* in_sizes, int n_in,
                              void* d_out, int out_size, void* d_ws, size_t ws_size,
                              hipStream_t stream)
{
  const float* obs     = (const float*)d_in[0];
  const float* act     = (const float*)d_in[1];
  const int*   task    = (const int*)  d_in[2];
  const float* bb_w1   = (const float*)d_in[3];
  const float* bb_b1   = (const float*)d_in[4];
  const float* bb_w2   = (const float*)d_in[5];
  const float* bb_b2   = (const float*)d_in[6];
  const float* ex_w1   = (const float*)d_in[7];
  const float* ex_b1   = (const float*)d_in[8];
  const float* ex_w2   = (const float*)d_in[9];
  const float* ex_b2   = (const float*)d_in[10];
  const float* key_mat = (const float*)d_in[11];
  const float* val_mat = (const float*)d_in[12];
  const float* tq      = (const float*)d_in[13];
  const float* tw_w1   = (const float*)d_in[14];
  const float* tw_b1   = (const float*)d_in[15];
  const float* tw_w2   = (const float*)d_in[16];
  const float* tw_b2   = (const float*)d_in[17];
  const float* tw_w3   = (const float*)d_in[18];
  const float* tw_b3   = (const float*)d_in[19];

  char* ws = (char*)d_ws;
  size_t off = 0;
  auto alloc = [&](size_t bytes){ void* p = ws + off; off += (bytes + 255) & ~(size_t)255; return p; };
  f16*   x16   = (f16*)  alloc((size_t)NB*64*2);
  f16*   h16   = (f16*)  alloc((size_t)NB*DP*2);
  f16*   e16   = (f16*)  alloc((size_t)NEXP*NB*DP*2);
  f16*   ti16  = (f16*)  alloc((size_t)NB*DP*2);
  float* scors = (float*)alloc((size_t)NB*NEXP*4);
  float* kq    = (float*)alloc((size_t)NEXP*NTASK*DP*4);
  f16*   bbw1T = (f16*)  alloc((size_t)DP*64*2);
  f16*   bbw2T = (f16*)  alloc((size_t)DP*DP*2);
  f16*   exw1T = (f16*)  alloc((size_t)NEXP*DP*DP*2);
  f16*   exw2T = (f16*)  alloc((size_t)NEXP*DP*DP*2);
  f16*   valT  = (f16*)  alloc((size_t)NEXP*DP*DP*2);
  f16*   tw1T  = (f16*)  alloc((size_t)DP*DP*2);
  f16*   tw2T  = (f16*)  alloc((size_t)DP*DP*2);
  (void)ws_size; (void)in_sizes; (void)n_in; (void)out_size;

  k_build_x<<<NB*64/256, 256, 0, stream>>>(obs, act, x16);
  k_transpose<<<dim3(13, 2, 1),  256, 0, stream>>>(bb_w1, bbw1T, 43, D, 64, DP);
  k_transpose<<<dim3(13,13, 1),  256, 0, stream>>>(bb_w2, bbw2T, D, D, DP, DP);
  k_transpose<<<dim3(13,13, 8),  256, 0, stream>>>(ex_w1, exw1T, D, D, DP, DP);
  k_transpose<<<dim3(13,13, 8),  256, 0, stream>>>(ex_w2, exw2T, D, D, DP, DP);
  k_transpose<<<dim3(13,13, 1),  256, 0, stream>>>(tw_w1, tw1T,  D, D, DP, DP);
  k_transpose<<<dim3(13,13, 1),  256, 0, stream>>>(tw_w2, tw2T,  D, D, DP, DP);
  k_val_pad<<<(NEXP*DP*DP + 255)/256, 256, 0, stream>>>(val_mat, valT);
  k_kq<<<NEXP, 256, 0, stream>>>(key_mat, tq, kq);

  k_backbone<<<NB/128, 512, 0, stream>>>(x16, bbw1T, bb_b1, bbw2T, bb_b2, h16);
  k_experts<<<dim3(NEXP, NB/128), 512, 0, stream>>>(h16, exw1T, ex_b1, exw2T, ex_b2,
                                                    e16, kq, task, scors);
  k_attn<<<dim3(2, NB/64), 256, 0, stream>>>(e16, valT, scors, ti16);
  k_mlp3<<<NB/128, 512, 0, stream>>>(ti16, tw1T, tw_b1, tw2T, tw_b2, tw_w3, tw_b3,
                                     (float*)d_out);
}